// Round 7
// baseline (706.976 us; speedup 1.0000x reference)
//
#include <hip/hip_runtime.h>
#include <math.h>

#define NB 4
#define NP 4096   // src points per batch
#define MP 4096   // tgt points per batch
#define NITER 10

typedef float f32x16 __attribute__((ext_vector_type(16)));

// one 64 B scalar load (4 tgt points) into a 16-SGPR tuple
#define ISSUE(B, P) asm volatile("s_load_dwordx16 %0, %1, 0x0" \
                                 : "=s"(B) : "s"(P))
// safe full drain: SMEM returns can be out-of-order, so only lgkmcnt(0) is
// reliable; tie all four buffers so consumption can't hoist above the wait
#define WAIT4(B0, B1, B2, B3) asm volatile("s_waitcnt lgkmcnt(0)" \
        : "+s"(B0), "+s"(B1), "+s"(B2), "+s"(B3))

// ---------------------------------------------------------------------------
// fp32 3x3 Kabsch from the 15 reduced sums (Σs, Σt, Σ s⊗t), lane-serial.
// ---------------------------------------------------------------------------
__device__ __forceinline__ void kabsch_f32(const float* s, float* RtL) {
    const float invN = 1.0f / (float)NP;
    float cs[3] = { s[0] * invN, s[1] * invN, s[2] * invN };
    float ct[3] = { s[3] * invN, s[4] * invN, s[5] * invN };
    float H[3][3];
    for (int d = 0; d < 3; ++d)
        for (int e = 0; e < 3; ++e)
            H[d][e] = s[6 + d * 3 + e] * invN - cs[d] * ct[e];

    float A[3][3];
    for (int i = 0; i < 3; ++i)
        for (int j = 0; j < 3; ++j)
            A[i][j] = H[0][i] * H[0][j] + H[1][i] * H[1][j] + H[2][i] * H[2][j];

    float V[3][3] = {{1, 0, 0}, {0, 1, 0}, {0, 0, 1}};
    for (int sweep = 0; sweep < 6; ++sweep) {
        float off = A[0][1] * A[0][1] + A[0][2] * A[0][2] + A[1][2] * A[1][2];
        if (off < 1e-16f) break;
        for (int pi = 0; pi < 3; ++pi) {
            const int p = (pi == 2) ? 1 : 0;
            const int q = (pi == 0) ? 1 : 2;
            float apq = A[p][q];
            if (fabsf(apq) < 1e-30f) continue;
            float theta = (A[q][q] - A[p][p]) / (2.0f * apq);
            float t = 1.0f / (fabsf(theta) + sqrtf(1.0f + theta * theta));
            if (theta < 0.0f) t = -t;
            float cth = 1.0f / sqrtf(1.0f + t * t);
            float sth = t * cth;
            float App = A[p][p], Aqq = A[q][q];
            A[p][p] = App - t * apq;
            A[q][q] = Aqq + t * apq;
            A[p][q] = A[q][p] = 0.0f;
            const int r = 3 - p - q;
            float Apr = A[p][r], Aqr = A[q][r];
            A[p][r] = A[r][p] = cth * Apr - sth * Aqr;
            A[q][r] = A[r][q] = sth * Apr + cth * Aqr;
            for (int i = 0; i < 3; ++i) {
                float Vip = V[i][p], Viq = V[i][q];
                V[i][p] = cth * Vip - sth * Viq;
                V[i][q] = sth * Vip + cth * Viq;
            }
        }
    }
    float lam[3] = { A[0][0], A[1][1], A[2][2] };
    for (int i = 0; i < 2; ++i)
        for (int j = i + 1; j < 3; ++j)
            if (lam[j] > lam[i]) {
                float tl = lam[i]; lam[i] = lam[j]; lam[j] = tl;
                for (int k = 0; k < 3; ++k) {
                    float tv = V[k][i]; V[k][i] = V[k][j]; V[k][j] = tv;
                }
            }

    float U[3][3];
    for (int k = 0; k < 3; ++k) {
        float w0 = H[0][0] * V[0][k] + H[0][1] * V[1][k] + H[0][2] * V[2][k];
        float w1 = H[1][0] * V[0][k] + H[1][1] * V[1][k] + H[1][2] * V[2][k];
        float w2 = H[2][0] * V[0][k] + H[2][1] * V[1][k] + H[2][2] * V[2][k];
        float nrm = sqrtf(w0 * w0 + w1 * w1 + w2 * w2);
        if (nrm > 1e-20f) {
            U[0][k] = w0 / nrm; U[1][k] = w1 / nrm; U[2][k] = w2 / nrm;
        } else {
            U[0][k] = U[1][0] * U[2][1] - U[2][0] * U[1][1];
            U[1][k] = U[2][0] * U[0][1] - U[0][0] * U[2][1];
            U[2][k] = U[0][0] * U[1][1] - U[1][0] * U[0][1];
        }
    }

    float detH = H[0][0] * (H[1][1] * H[2][2] - H[1][2] * H[2][1])
               - H[0][1] * (H[1][0] * H[2][2] - H[1][2] * H[2][0])
               + H[0][2] * (H[1][0] * H[2][1] - H[1][1] * H[2][0]);
    float sgn = (detH < 0.0f) ? -1.0f : 1.0f;

    float R[3][3];
    for (int i = 0; i < 3; ++i)
        for (int j = 0; j < 3; ++j)
            R[i][j] = V[i][0] * U[j][0] + V[i][1] * U[j][1] + sgn * V[i][2] * U[j][2];
    float tv[3];
    for (int i = 0; i < 3; ++i)
        tv[i] = ct[i] - (R[i][0] * cs[0] + R[i][1] * cs[1] + R[i][2] * cs[2]);

    for (int i = 0; i < 3; ++i)
        for (int j = 0; j < 3; ++j)
            RtL[i * 3 + j] = R[i][j];
    for (int i = 0; i < 3; ++i) RtL[9 + i] = tv[i];
}

// Build tgt4 = (x,y,z,|t|^2) and zero the barrier/accumulator state
// (d_ws is poisoned 0xAA before every timed call).
__global__ __launch_bounds__(256) void icp_init(const float* __restrict__ tgt,
                                                float4* __restrict__ tgt4,
                                                float* __restrict__ acc,
                                                unsigned* __restrict__ cnt) {
    int j = blockIdx.x * 256 + threadIdx.x;       // 0..16383
    float x = tgt[j * 3 + 0];
    float y = tgt[j * 3 + 1];
    float z = tgt[j * 3 + 2];
    tgt4[j] = make_float4(x, y, z, x * x + y * y + z * z);
    if (blockIdx.x == 0) {
        for (int k = threadIdx.x; k < NITER * NB * 16; k += 256) acc[k] = 0.0f;
        if (threadIdx.x < NITER) cnt[threadIdx.x] = 0u;
    }
}

// ---------------------------------------------------------------------------
// Persistent fused ICP: 256 blocks (batch b = blk>>6, src-group g = blk&63)
// x 1024 threads (16 waves). All waves own the same 64 src points (in
// registers for the whole kernel); wave w scans tgt chunk [w*256,+256)
// streamed through 4 x 16-SGPR buffers (s_load_dwordx16, lgkmcnt(0)-safe
// supergroups of 16 points, reissue-before-consume overlap).
// Key = float d with low 12 mantissa bits replaced by the tgt index; fminf
// (v_min3_f32) is the running argmin. Per-iteration device barrier is a
// hand-rolled atomic arrive+spin (all 256 blocks co-resident: 16 waves <=
// 32/CU capacity); batch sums accumulate via device-scope float atomicAdd.
// ---------------------------------------------------------------------------
__global__ __launch_bounds__(1024) void icp_persist(
        const float* __restrict__ src,
        const float4* __restrict__ tgt4,
        float* __restrict__ acc,          // [NITER][NB][16]
        unsigned* __restrict__ cnt,       // [NITER]
        float* __restrict__ out) {
    __shared__ unsigned CK[1024];
    __shared__ float RtL[12];

    const int blk = blockIdx.x;
    const int b   = blk >> 6;
    const int g   = blk & 63;
    const int tid = threadIdx.x;
    const int w   = tid >> 6;             // wave 0..15
    const int l   = tid & 63;
    const int gsrc = b * NP + g * 64 + l;

    float px = src[gsrc * 3 + 0];
    float py = src[gsrc * 3 + 1];
    float pz = src[gsrc * 3 + 2];

    const float4* tb4 = tgt4 + b * MP;
    const char* pb = (const char*)tb4 +
                     __builtin_amdgcn_readfirstlane((unsigned)(w << 12));

    for (int it = 0; it < NITER; ++it) {
        const float nx = -2.0f * px, ny = -2.0f * py, nz = -2.0f * pz;
        float best = __uint_as_float(0x7F7FFFFFu);   // FLT_MAX

        f32x16 B0, B1, B2, B3;
        ISSUE(B0, pb);
        ISSUE(B1, pb + 64);
        ISSUE(B2, pb + 128);
        ISSUE(B3, pb + 192);

        // key: d with low 12 bits = local tgt index (0..255); float order
        // == (quantized d, idx); w bits OR'ed in after the scan.
#define KEY(Bf, jj, LI)                                                     \
        __uint_as_float((__float_as_uint(                                   \
            fmaf(nx, Bf[4*(jj)+0], fmaf(ny, Bf[4*(jj)+1],                   \
                 fmaf(nz, Bf[4*(jj)+2], Bf[4*(jj)+3])))) & 0xFFFFF000u)     \
            | (unsigned)(LI))
#define CONS4(Bf, LBASE) do {                                               \
            float k0 = KEY(Bf, 0, (LBASE) + 0);                             \
            float k1 = KEY(Bf, 1, (LBASE) + 1);                             \
            float k2 = KEY(Bf, 2, (LBASE) + 2);                             \
            float k3 = KEY(Bf, 3, (LBASE) + 3);                             \
            best = fminf(fminf(k0, k1), best);                              \
            best = fminf(fminf(k2, k3), best);                              \
        } while (0)

        #pragma unroll
        for (int sg = 0; sg < 16; ++sg) {
            WAIT4(B0, B1, B2, B3);
            const char* nb = pb + (sg + 1) * 256;
            CONS4(B0, sg * 16 + 0);
            CONS4(B1, sg * 16 + 4);
            if (sg < 15) { ISSUE(B0, nb); ISSUE(B1, nb + 64); }
            CONS4(B2, sg * 16 + 8);
            CONS4(B3, sg * 16 + 12);
            if (sg < 15) { ISSUE(B2, nb + 128); ISSUE(B3, nb + 192); }
        }
#undef CONS4
#undef KEY

        CK[tid] = __float_as_uint(best) | (unsigned)(w << 8);
        __syncthreads();

        // ---- wave 0: combine 16 chunk winners, reduce, barrier, solve ----
        if (w == 0) {
            float kmin = __uint_as_float(CK[l]);
            #pragma unroll
            for (int k = 1; k < 16; ++k)
                kmin = fminf(kmin, __uint_as_float(CK[k * 64 + l]));
            const int idx = __float_as_uint(kmin) & 0xFFF;
            float4 mt = tb4[idx];
            const float tx = mt.x, ty = mt.y, tz = mt.z;

            float v[15];
            v[0]  = px;      v[1]  = py;      v[2]  = pz;
            v[3]  = tx;      v[4]  = ty;      v[5]  = tz;
            v[6]  = px * tx; v[7]  = px * ty; v[8]  = px * tz;
            v[9]  = py * tx; v[10] = py * ty; v[11] = py * tz;
            v[12] = pz * tx; v[13] = pz * ty; v[14] = pz * tz;
            #pragma unroll
            for (int k = 0; k < 15; ++k) {
                float s = v[k];
                s += __shfl_down(s, 32);
                s += __shfl_down(s, 16);
                s += __shfl_down(s, 8);
                s += __shfl_down(s, 4);
                s += __shfl_down(s, 2);
                s += __shfl_down(s, 1);
                v[k] = s;
            }
            if (l == 0) {
                float* ab = acc + (it * NB + b) * 16;
                #pragma unroll
                for (int k = 0; k < 15; ++k) atomicAdd(&ab[k], v[k]);
                __threadfence();
                atomicAdd(&cnt[it], 1u);
                while (atomicAdd(&cnt[it], 0u) < 256u)
                    __builtin_amdgcn_s_sleep(4);
                __threadfence();
                float sm[15];
                #pragma unroll
                for (int k = 0; k < 15; ++k) sm[k] = atomicAdd(&ab[k], 0.0f);
                kabsch_f32(sm, RtL);
            }
        }
        __syncthreads();

        // ---- transform own point: p <- p @ R + t ----
        {
            float x = px, y = py, z = pz;
            px = x * RtL[0] + y * RtL[3] + z * RtL[6] + RtL[9];
            py = x * RtL[1] + y * RtL[4] + z * RtL[7] + RtL[10];
            pz = x * RtL[2] + y * RtL[5] + z * RtL[8] + RtL[11];
        }
        // next iteration's CK write happens only after this point; safe.
    }

    // ---- outputs: R [4,3,3] (36), t [4,3] (12), points [4,4096,3] ----
    if (w == 0) {
        out[48 + gsrc * 3 + 0] = px;
        out[48 + gsrc * 3 + 1] = py;
        out[48 + gsrc * 3 + 2] = pz;
    }
    if (g == 0 && tid < 9)  out[b * 9 + tid]      = RtL[tid];
    if (g == 0 && tid < 3)  out[36 + b * 3 + tid] = RtL[9 + tid];
}

extern "C" void kernel_launch(void* const* d_in, const int* in_sizes, int n_in,
                              void* d_out, int out_size, void* d_ws, size_t ws_size,
                              hipStream_t stream) {
    const float* src = (const float*)d_in[0];
    const float* tgt = (const float*)d_in[1];
    float* out = (float*)d_out;

    float* W      = (float*)d_ws;
    float4* tgt4  = (float4*)W;            // 65536 floats (256 KB)
    float* acc    = W + 65536;             // NITER*NB*16 = 640 floats
    unsigned* cnt = (unsigned*)(W + 65536 + 640);   // NITER u32

    icp_init<<<64, 256, 0, stream>>>(tgt, tgt4, acc, cnt);
    icp_persist<<<256, 1024, 0, stream>>>(src, tgt4, acc, cnt, out);
}

// Round 8
// 194.526 us; speedup vs baseline: 3.6343x; 3.6343x over previous
//
#include <hip/hip_runtime.h>
#include <math.h>

#define NB 4
#define NP 4096   // src points per batch
#define MP 4096   // tgt points per batch

typedef __bf16 bf16x8 __attribute__((ext_vector_type(8)));
typedef float  f32x16 __attribute__((ext_vector_type(16)));

// round-to-nearest-even fp32 -> bf16 (as raw u16)
static __device__ __forceinline__ unsigned short bh(float f) {
    unsigned u = __float_as_uint(f);
    unsigned r = (u + 0x7FFFu + ((u >> 16) & 1u)) >> 16;
    return (unsigned short)r;
}
static __device__ __forceinline__ float hf(unsigned short h) {
    return __uint_as_float(((unsigned)h) << 16);
}

// ---------------------------------------------------------------------------
// fp32 3x3 Kabsch from the 15 reduced sums (identical to R4-R6).
// ---------------------------------------------------------------------------
__device__ __forceinline__ void kabsch_f32(const float* s, float* RtL) {
    const float invN = 1.0f / (float)NP;
    float cs[3] = { s[0] * invN, s[1] * invN, s[2] * invN };
    float ct[3] = { s[3] * invN, s[4] * invN, s[5] * invN };
    float H[3][3];
    for (int d = 0; d < 3; ++d)
        for (int e = 0; e < 3; ++e)
            H[d][e] = s[6 + d * 3 + e] * invN - cs[d] * ct[e];

    float A[3][3];
    for (int i = 0; i < 3; ++i)
        for (int j = 0; j < 3; ++j)
            A[i][j] = H[0][i] * H[0][j] + H[1][i] * H[1][j] + H[2][i] * H[2][j];

    float V[3][3] = {{1, 0, 0}, {0, 1, 0}, {0, 0, 1}};
    for (int sweep = 0; sweep < 8; ++sweep) {
        float off = A[0][1] * A[0][1] + A[0][2] * A[0][2] + A[1][2] * A[1][2];
        if (off < 1e-16f) break;
        for (int pi = 0; pi < 3; ++pi) {
            const int p = (pi == 2) ? 1 : 0;
            const int q = (pi == 0) ? 1 : 2;
            float apq = A[p][q];
            if (fabsf(apq) < 1e-30f) continue;
            float theta = (A[q][q] - A[p][p]) / (2.0f * apq);
            float t = 1.0f / (fabsf(theta) + sqrtf(1.0f + theta * theta));
            if (theta < 0.0f) t = -t;
            float cth = 1.0f / sqrtf(1.0f + t * t);
            float sth = t * cth;
            float App = A[p][p], Aqq = A[q][q];
            A[p][p] = App - t * apq;
            A[q][q] = Aqq + t * apq;
            A[p][q] = A[q][p] = 0.0f;
            const int r = 3 - p - q;
            float Apr = A[p][r], Aqr = A[q][r];
            A[p][r] = A[r][p] = cth * Apr - sth * Aqr;
            A[q][r] = A[r][q] = sth * Apr + cth * Aqr;
            for (int i = 0; i < 3; ++i) {
                float Vip = V[i][p], Viq = V[i][q];
                V[i][p] = cth * Vip - sth * Viq;
                V[i][q] = sth * Vip + cth * Viq;
            }
        }
    }
    float lam[3] = { A[0][0], A[1][1], A[2][2] };
    for (int i = 0; i < 2; ++i)
        for (int j = i + 1; j < 3; ++j)
            if (lam[j] > lam[i]) {
                float tl = lam[i]; lam[i] = lam[j]; lam[j] = tl;
                for (int k = 0; k < 3; ++k) {
                    float tv = V[k][i]; V[k][i] = V[k][j]; V[k][j] = tv;
                }
            }

    float U[3][3];
    for (int k = 0; k < 3; ++k) {
        float w0 = H[0][0] * V[0][k] + H[0][1] * V[1][k] + H[0][2] * V[2][k];
        float w1 = H[1][0] * V[0][k] + H[1][1] * V[1][k] + H[1][2] * V[2][k];
        float w2 = H[2][0] * V[0][k] + H[2][1] * V[1][k] + H[2][2] * V[2][k];
        float nrm = sqrtf(w0 * w0 + w1 * w1 + w2 * w2);
        if (nrm > 1e-20f) {
            U[0][k] = w0 / nrm; U[1][k] = w1 / nrm; U[2][k] = w2 / nrm;
        } else {
            U[0][k] = U[1][0] * U[2][1] - U[2][0] * U[1][1];
            U[1][k] = U[2][0] * U[0][1] - U[0][0] * U[2][1];
            U[2][k] = U[0][0] * U[1][1] - U[1][0] * U[0][1];
        }
    }

    float detH = H[0][0] * (H[1][1] * H[2][2] - H[1][2] * H[2][1])
               - H[0][1] * (H[1][0] * H[2][2] - H[1][2] * H[2][0])
               + H[0][2] * (H[1][0] * H[2][1] - H[1][1] * H[2][0]);
    float sgn = (detH < 0.0f) ? -1.0f : 1.0f;

    float R[3][3];
    for (int i = 0; i < 3; ++i)
        for (int j = 0; j < 3; ++j)
            R[i][j] = V[i][0] * U[j][0] + V[i][1] * U[j][1] + sgn * V[i][2] * U[j][2];
    float tv[3];
    for (int i = 0; i < 3; ++i)
        tv[i] = ct[i] - (R[i][0] * cs[0] + R[i][1] * cs[1] + R[i][2] * cs[2]);

    for (int i = 0; i < 3; ++i)
        for (int j = 0; j < 3; ++j)
            RtL[i * 3 + j] = R[i][j];
    for (int i = 0; i < 3; ++i) RtL[9 + i] = tv[i];
}

// ---------------------------------------------------------------------------
// Init: build tgt4 (x,y,z,|t|^2) for gathers AND the pre-packed bf16 hi/lo
// B-fragments for mfma_f32_32x32x16_bf16.
// K-slot semantics (A x B pairing):
//   k0..3  : (-2sx){h,l,h,l} x tx{h,h,l,l}   -> -2 sx*tx   (all cross terms)
//   k4..7  : same for y;  k8..11: same for z
//   k12,13 : 1 x |t|^2{h,l}                   -> +|t|^2
//   k14,15 : (|s|^2+1){h,l} x 1               -> +|s|^2+1  (positivity)
// B lane layout (assumed mirror of A): B[n=lane&31][k=(lane>>5)*8+j].
// Bbuf: [b][tile(128)][lane(64)] x uint4 (8 bf16 each) = 512 KB.
// ---------------------------------------------------------------------------
__global__ __launch_bounds__(256) void icp_init(const float* __restrict__ tgt,
                                                float4* __restrict__ tgt4,
                                                uint4* __restrict__ Bbuf) {
    const int t    = blockIdx.x * 256 + threadIdx.x;   // 0..32767
    const int b    = t >> 13;
    const int rem  = t & 8191;
    const int tile = rem >> 6;        // 0..127 (32 tgt pts each)
    const int lane = rem & 63;
    const int n    = lane & 31;
    const int h    = lane >> 5;
    const int gt   = b * MP + tile * 32 + n;

    float x = tgt[gt * 3 + 0];
    float y = tgt[gt * 3 + 1];
    float z = tgt[gt * 3 + 2];
    float wv = x * x + y * y + z * z;

    unsigned short xh = bh(x), xl = bh(x - hf(xh));
    unsigned short yh = bh(y), yl = bh(y - hf(yh));
    unsigned short zh = bh(z), zl = bh(z - hf(zh));
    unsigned short wh = bh(wv), wl = bh(wv - hf(wh));
    const unsigned short ONE = 0x3F80;

    unsigned short s0, s1, s2, s3, s4, s5, s6, s7;
    if (h == 0) { s0 = xh; s1 = xh; s2 = xl; s3 = xl;
                  s4 = yh; s5 = yh; s6 = yl; s7 = yl; }
    else        { s0 = zh; s1 = zh; s2 = zl; s3 = zl;
                  s4 = wh; s5 = wl; s6 = ONE; s7 = ONE; }
    uint4 u;
    u.x = (unsigned)s0 | ((unsigned)s1 << 16);
    u.y = (unsigned)s2 | ((unsigned)s3 << 16);
    u.z = (unsigned)s4 | ((unsigned)s5 << 16);
    u.w = (unsigned)s6 | ((unsigned)s7 << 16);
    Bbuf[t] = u;

    if (h == 0) tgt4[gt] = make_float4(x, y, z, wv);
}

// ---------------------------------------------------------------------------
// One ICP iteration per dispatch. 256 blocks (batch b = blk>>6, src-group
// g = blk&63; lane l owns src point l), 1024 threads = 16 waves.
// Wave w: src-tile ts = w&1 (32 src), tgt-range tr = w>>1 (16 tiles x 32 tgt).
// Per tile: 1 coalesced uint4 load (B-frag) + 1 mfma_32x32x16_bf16 giving
// 1024 distances d = |s-t|^2 + 1 (hi/lo split, err ~2^-16) + 16x(and_or+min)
// key epilogue. Cross-col shfl_xor reduce, CK combine, wave-0 15-sum.
// Prologue: wave 0 redundantly solves prev (R,t) (fp32 Kabsch).
// ---------------------------------------------------------------------------
__global__ __launch_bounds__(1024) void icp_scan(
        const float* __restrict__ src,
        const float4* __restrict__ tgt4,
        const uint4* __restrict__ Bbuf,
        float* __restrict__ S,            // [NB*NP*3] transformed points
        const float* __restrict__ pprev,  // [256][16] prev partials
        float* __restrict__ pout,         // [256][16] this iter's partials
        int first) {
    __shared__ unsigned CK[512];          // [tr(8)][src(64)]
    __shared__ float RtL[12];

    const int blk = blockIdx.x;
    const int b   = blk >> 6;
    const int g   = blk & 63;
    const int tid = threadIdx.x;
    const int w   = tid >> 6;
    const int l   = tid & 63;
    const int ts  = w & 1;
    const int tr  = w >> 1;
    const int gsrc = b * NP + g * 64 + l;

    // ---- prologue: wave 0 redundantly solves prev iteration's (R,t) ----
    if (w == 0) {
        if (first) {
            if (l < 12) RtL[l] = (l == 0 || l == 4 || l == 8) ? 1.0f : 0.0f;
        } else {
            const float4* rp = (const float4*)(pprev + (b * 64 + l) * 16);
            float4 r0 = rp[0], r1 = rp[1], r2 = rp[2], r3 = rp[3];
            float sm[15] = { r0.x, r0.y, r0.z, r0.w, r1.x, r1.y, r1.z, r1.w,
                             r2.x, r2.y, r2.z, r2.w, r3.x, r3.y, r3.z };
            #pragma unroll
            for (int k = 0; k < 15; ++k) {
                float v = sm[k];
                v += __shfl_down(v, 32);
                v += __shfl_down(v, 16);
                v += __shfl_down(v, 8);
                v += __shfl_down(v, 4);
                v += __shfl_down(v, 2);
                v += __shfl_down(v, 1);
                sm[k] = v;
            }
            if (l == 0) kabsch_f32(sm, RtL);
        }
    }
    __syncthreads();

    // ---- transform own point; wave 1 persists it for the next iteration ----
    float px, py, pz;
    {
        const float* P = first ? src : S;
        float x = P[gsrc * 3 + 0];
        float y = P[gsrc * 3 + 1];
        float z = P[gsrc * 3 + 2];
        px = x * RtL[0] + y * RtL[3] + z * RtL[6] + RtL[9];
        py = x * RtL[1] + y * RtL[4] + z * RtL[7] + RtL[10];
        pz = x * RtL[2] + y * RtL[5] + z * RtL[8] + RtL[11];
    }
    if (w == 1) {
        S[gsrc * 3 + 0] = px;
        S[gsrc * 3 + 1] = py;
        S[gsrc * 3 + 2] = pz;
    }

    // ---- build A-fragment: A[m=lane&31][k=(lane>>5)*8+j] ----
    const int h = l >> 5;
    union { unsigned short s[8]; bf16x8 v; } Af;
    {
        const int j3 = ts * 32 + (l & 31);     // src point this lane's m maps to
        float pxj = __shfl(px, j3);
        float pyj = __shfl(py, j3);
        float pzj = __shfl(pz, j3);
        float ax = -2.0f * pxj, ay = -2.0f * pyj, az = -2.0f * pzj;
        float qv = pxj * pxj + pyj * pyj + pzj * pzj + 1.0f;
        unsigned short axh = bh(ax), axl = bh(ax - hf(axh));
        unsigned short ayh = bh(ay), ayl = bh(ay - hf(ayh));
        unsigned short azh = bh(az), azl = bh(az - hf(azh));
        unsigned short qh  = bh(qv), ql  = bh(qv - hf(qh));
        const unsigned short ONE = 0x3F80;
        if (h == 0) {
            Af.s[0] = axh; Af.s[1] = axl; Af.s[2] = axh; Af.s[3] = axl;
            Af.s[4] = ayh; Af.s[5] = ayl; Af.s[6] = ayh; Af.s[7] = ayl;
        } else {
            Af.s[0] = azh; Af.s[1] = azl; Af.s[2] = azh; Af.s[3] = azl;
            Af.s[4] = ONE; Af.s[5] = ONE; Af.s[6] = qh;  Af.s[7] = ql;
        }
    }

    // ---- 16-tile scan on the MFMA pipe ----
    f32x16 zero;
    #pragma unroll
    for (int i = 0; i < 16; ++i) zero[i] = 0.0f;

    float best[16];
    #pragma unroll
    for (int r = 0; r < 16; ++r) best[r] = __uint_as_float(0x7F7FFFFFu);

    const uint4* Bw = Bbuf + (b * 128 + tr * 16) * 64;
    const int col = l & 31;

    uint4 fb[4];
    fb[0] = Bw[l];
    fb[1] = Bw[64 + l];
    fb[2] = Bw[128 + l];
    fb[3] = Bw[192 + l];

    #pragma unroll
    for (int t = 0; t < 16; ++t) {
        bf16x8 Bf = __builtin_bit_cast(bf16x8, fb[t & 3]);
        if (t < 12) fb[t & 3] = Bw[(t + 4) * 64 + l];
        f32x16 d16 = __builtin_amdgcn_mfma_f32_32x32x16_bf16(Af.v, Bf, zero,
                                                             0, 0, 0);
        const unsigned idxk = (unsigned)((tr * 16 + t) * 32 + col);
        #pragma unroll
        for (int r = 0; r < 16; ++r) {
            float key = __uint_as_float(
                (__float_as_uint(d16[r]) & 0xFFFFF000u) | idxk);
            best[r] = fminf(best[r], key);
        }
    }

    // ---- reduce across the 32 columns (lanes within each half-wave) ----
    #pragma unroll
    for (int r = 0; r < 16; ++r) {
        float v = best[r];
        v = fminf(v, __shfl_xor(v, 1));
        v = fminf(v, __shfl_xor(v, 2));
        v = fminf(v, __shfl_xor(v, 4));
        v = fminf(v, __shfl_xor(v, 8));
        v = fminf(v, __shfl_xor(v, 16));
        best[r] = v;
    }
    if ((l & 31) == 0) {
        #pragma unroll
        for (int r = 0; r < 16; ++r) {
            const int row = (r & 3) + 8 * (r >> 2) + 4 * h;
            CK[tr * 64 + ts * 32 + row] = __float_as_uint(best[r]);
        }
    }
    __syncthreads();

    // ---- wave 0: combine 8 tgt-ranges, gather match, 15-sum ----
    if (w == 0) {
        unsigned kb = CK[l];
        #pragma unroll
        for (int k = 1; k < 8; ++k) {
            unsigned kk = CK[k * 64 + l];
            kb = kk < kb ? kk : kb;
        }
        const int idx = kb & 0xFFF;
        float4 mt = tgt4[b * MP + idx];
        const float tx = mt.x, ty = mt.y, tz = mt.z;

        float v[15];
        v[0]  = px;      v[1]  = py;      v[2]  = pz;
        v[3]  = tx;      v[4]  = ty;      v[5]  = tz;
        v[6]  = px * tx; v[7]  = px * ty; v[8]  = px * tz;
        v[9]  = py * tx; v[10] = py * ty; v[11] = py * tz;
        v[12] = pz * tx; v[13] = pz * ty; v[14] = pz * tz;
        #pragma unroll
        for (int k = 0; k < 15; ++k) {
            float s = v[k];
            s += __shfl_down(s, 32);
            s += __shfl_down(s, 16);
            s += __shfl_down(s, 8);
            s += __shfl_down(s, 4);
            s += __shfl_down(s, 2);
            s += __shfl_down(s, 1);
            v[k] = s;
        }
        if (l == 0) {
            float* pp = pout + blk * 16;
            #pragma unroll
            for (int k = 0; k < 15; ++k) pp[k] = v[k];
        }
    }
}

// Final: solve iteration-10's (R,t) (redundant per block), apply, write out.
// out layout: R [4,3,3] flat (36), t [4,3] flat (12), points [4,4096,3].
__global__ __launch_bounds__(256) void icp_final(
        const float* __restrict__ S,
        const float* __restrict__ plast,
        float* __restrict__ out) {
    __shared__ float RtL[12];
    const int bk  = blockIdx.x;
    const int tid = threadIdx.x;
    const int gid = bk * 256 + tid;               // 0..16383
    const int b   = gid >> 12;

    if (tid < 64) {
        const float4* rp = (const float4*)(plast + (b * 64 + tid) * 16);
        float4 r0 = rp[0], r1 = rp[1], r2 = rp[2], r3 = rp[3];
        float sm[15] = { r0.x, r0.y, r0.z, r0.w, r1.x, r1.y, r1.z, r1.w,
                         r2.x, r2.y, r2.z, r2.w, r3.x, r3.y, r3.z };
        #pragma unroll
        for (int k = 0; k < 15; ++k) {
            float v = sm[k];
            v += __shfl_down(v, 32);
            v += __shfl_down(v, 16);
            v += __shfl_down(v, 8);
            v += __shfl_down(v, 4);
            v += __shfl_down(v, 2);
            v += __shfl_down(v, 1);
            sm[k] = v;
        }
        if (tid == 0) kabsch_f32(sm, RtL);
    }
    __syncthreads();

    float x = S[gid * 3 + 0];
    float y = S[gid * 3 + 1];
    float z = S[gid * 3 + 2];
    out[48 + gid * 3 + 0] = x * RtL[0] + y * RtL[3] + z * RtL[6] + RtL[9];
    out[48 + gid * 3 + 1] = x * RtL[1] + y * RtL[4] + z * RtL[7] + RtL[10];
    out[48 + gid * 3 + 2] = x * RtL[2] + y * RtL[5] + z * RtL[8] + RtL[11];
    if ((bk & 15) == 0) {
        if (tid < 9) out[b * 9 + tid] = RtL[tid];
        if (tid < 3) out[36 + b * 3 + tid] = RtL[9 + tid];
    }
}

extern "C" void kernel_launch(void* const* d_in, const int* in_sizes, int n_in,
                              void* d_out, int out_size, void* d_ws, size_t ws_size,
                              hipStream_t stream) {
    const float* src = (const float*)d_in[0];
    const float* tgt = (const float*)d_in[1];
    float* out = (float*)d_out;

    float* W     = (float*)d_ws;
    float4* tgt4 = (float4*)W;                       // 65536 floats
    uint4*  Bbuf = (uint4*)(W + 65536);              // 131072 floats (512 KB)
    float*  S    = W + 65536 + 131072;               // 49152 floats
    float*  pA   = S + 49152;                        // 4096 floats
    float*  pB   = pA + 4096;                        // 4096 floats
    float* bufs[2] = { pA, pB };

    icp_init<<<128, 256, 0, stream>>>(tgt, tgt4, Bbuf);
    for (int k = 0; k < 10; ++k) {
        icp_scan<<<256, 1024, 0, stream>>>(src, tgt4, Bbuf, S,
                                           bufs[(k + 1) & 1], bufs[k & 1],
                                           k == 0 ? 1 : 0);
    }
    icp_final<<<64, 256, 0, stream>>>(S, bufs[1], out);
}